// Round 2
// baseline (86.768 us; speedup 1.0000x reference)
//
#include <hip/hip_runtime.h>

#define NUM_HASHES 4
#define KVALS 512
#define DIM 256

typedef float v4f __attribute__((ext_vector_type(4)));
typedef int   v4i __attribute__((ext_vector_type(4)));

// One wave (64 lanes) per (b,s) position. Lane i handles floats [4i, 4i+4).
// Tables (weight_table 8KB, emb_table 263KB) are cache-resident; the kernel
// is bound by the 64 MiB output write -> nontemporal stores.
__global__ __launch_bounds__(256) void HashEmbedding_44976897523736_kernel(
    const int* __restrict__ x,          // [num_pos, 4] int32
    const float* __restrict__ wt,       // [2052] (weight_table flattened)
    const float* __restrict__ emb,      // [257, 256]
    float* __restrict__ out,            // [num_pos, 256]
    int num_pos)
{
    int tid  = blockIdx.x * blockDim.x + threadIdx.x;
    int pos  = tid >> 6;   // wave-per-position
    int lane = tid & 63;
    if (pos >= num_pos) return;

    // All 64 lanes load the same 16B -> L1 broadcast.
    const v4i xi = *reinterpret_cast<const v4i*>(x + pos * NUM_HASHES);

    // offsets: h * (K+1) = h * 513
    const float w0 = wt[xi.x];
    const float w1 = wt[xi.y + 513];
    const float w2 = wt[xi.z + 1026];
    const float w3 = wt[xi.w + 1539];

    const v4f e0 = reinterpret_cast<const v4f*>(emb + (xi.x >> 1) * DIM)[lane];
    const v4f e1 = reinterpret_cast<const v4f*>(emb + (xi.y >> 1) * DIM)[lane];
    const v4f e2 = reinterpret_cast<const v4f*>(emb + (xi.z >> 1) * DIM)[lane];
    const v4f e3 = reinterpret_cast<const v4f*>(emb + (xi.w >> 1) * DIM)[lane];

    v4f r = w0 * e0 + w1 * e1 + w2 * e2 + w3 * e3;

    v4f* op = reinterpret_cast<v4f*>(out + (size_t)pos * DIM) + lane;
    __builtin_nontemporal_store(r, op);
}

extern "C" void kernel_launch(void* const* d_in, const int* in_sizes, int n_in,
                              void* d_out, int out_size, void* d_ws, size_t ws_size,
                              hipStream_t stream) {
    const int*   x   = (const int*)d_in[0];
    const float* wt  = (const float*)d_in[1];
    const float* emb = (const float*)d_in[2];
    float*       out = (float*)d_out;

    const int num_pos = in_sizes[0] / NUM_HASHES;       // 16*4096 = 65536
    const int total_threads = num_pos * 64;             // one wave per position
    const int block = 256;
    const int grid  = (total_threads + block - 1) / block;

    HashEmbedding_44976897523736_kernel<<<grid, block, 0, stream>>>(
        x, wt, emb, out, num_pos);
}

// Round 3
// 86.093 us; speedup vs baseline: 1.0078x; 1.0078x over previous
//
#include <hip/hip_runtime.h>

#define NUM_HASHES 4
#define DIM 256

typedef float v4f __attribute__((ext_vector_type(4)));

// Grid-stride, one wave per position per iteration. `pos` is forced
// wave-uniform so x/weight loads become scalar (SMEM) loads and emb gathers
// are SGPR-base + lane-offset global_load_dwordx4. Loop gives the compiler
// independent iterations to software-pipeline (MLP beyond occupancy).
// Output (64 MiB, write-once) goes out via nontemporal stores so the 263 KB
// emb table stays L2-resident.
__global__ __launch_bounds__(256) void HashEmbedding_44976897523736_kernel(
    const int* __restrict__ x,          // [num_pos, 4] int32
    const float* __restrict__ wt,       // [2052]
    const float* __restrict__ emb,      // [257, 256]
    float* __restrict__ out,            // [num_pos, 256]
    int num_pos, int num_waves)
{
    const int lane = threadIdx.x & 63;
    const int wave = __builtin_amdgcn_readfirstlane(
        blockIdx.x * (blockDim.x >> 6) + (threadIdx.x >> 6));

    #pragma unroll 2
    for (int p = wave; p < num_pos; p += num_waves) {
        // wave-uniform address -> s_load_dwordx4
        const int4 xi = *reinterpret_cast<const int4*>(x + p * NUM_HASHES);
        const int i0 = __builtin_amdgcn_readfirstlane(xi.x);
        const int i1 = __builtin_amdgcn_readfirstlane(xi.y);
        const int i2 = __builtin_amdgcn_readfirstlane(xi.z);
        const int i3 = __builtin_amdgcn_readfirstlane(xi.w);

        // uniform -> s_load_dword from the 8 KB weight table
        const float w0 = wt[i0];
        const float w1 = wt[i1 + 513];
        const float w2 = wt[i2 + 1026];
        const float w3 = wt[i3 + 1539];

        // SGPR row base + lane*16B offset -> coalesced 1 KB row reads (L2-hit)
        const v4f e0 = reinterpret_cast<const v4f*>(emb + (i0 >> 1) * DIM)[lane];
        const v4f e1 = reinterpret_cast<const v4f*>(emb + (i1 >> 1) * DIM)[lane];
        const v4f e2 = reinterpret_cast<const v4f*>(emb + (i2 >> 1) * DIM)[lane];
        const v4f e3 = reinterpret_cast<const v4f*>(emb + (i3 >> 1) * DIM)[lane];

        v4f r = w0 * e0 + w1 * e1 + w2 * e2 + w3 * e3;

        __builtin_nontemporal_store(
            r, reinterpret_cast<v4f*>(out + (size_t)p * DIM) + lane);
    }
}

extern "C" void kernel_launch(void* const* d_in, const int* in_sizes, int n_in,
                              void* d_out, int out_size, void* d_ws, size_t ws_size,
                              hipStream_t stream) {
    const int*   x   = (const int*)d_in[0];
    const float* wt  = (const float*)d_in[1];
    const float* emb = (const float*)d_in[2];
    float*       out = (float*)d_out;

    const int num_pos = in_sizes[0] / NUM_HASHES;   // 65536

    // 2048 blocks x 4 waves = 8192 waves (8 waves/SIMD across 256 CUs),
    // 8 grid-stride iterations per wave at num_pos=65536.
    const int block = 256;
    int blocks = 2048;
    int num_waves = blocks * (block / 64);
    if (num_waves > num_pos) {                      // tiny-input fallback
        blocks = (num_pos * 64 + block - 1) / block;
        if (blocks < 1) blocks = 1;
        num_waves = blocks * (block / 64);
    }

    HashEmbedding_44976897523736_kernel<<<blocks, block, 0, stream>>>(
        x, wt, emb, out, num_pos, num_waves);
}